// Round 14
// baseline (127.384 us; speedup 1.0000x reference)
//
#include <hip/hip_runtime.h>
#include <hip/hip_bf16.h>

// FFN: out = x + fc2(relu(fc1(LN(x)))), x:(ntok,16) fp32, ntok % 1024 == 0.
// R16: reg-staging swap. R15 (DMA global_load_lds, depth-3, counted vmcnt)
// saturated at ~33us: staged-ahead bytes (96KB/CU) far exceed what Little's
// law needs, yet achieved BW ~3 TB/s vs 6.3 for the m13 float4 copy (vector
// loads) on this chip. Theory: global_load_lds serves its 16 line-fills with
// limited intra-op concurrency (in-order LDS delivery) -> per-op service
// floor that depth cannot hide. Swap the load engine, keep the schedule:
//  - LOADX(j): 2x global_load_dwordx4 into reg slot j&3 (8 VGPR/slot, 4
//    slots): per-lane 16B at chunk l and chunk 64+l of the 2KB tile.
//  - before consuming tile it: counted vmcnt wait (R15 schedule VERBATIM —
//    LOADX is 2 VMEM ops exactly like STAGE was), then 2x ds_write_b128
//    into ONE wave-private 2KB LDS slot -> LDS layout bit-identical to R15,
//    all read/compute code unchanged. LDS 32KB -> 8KB/block.
//  - asm("" ::: "memory") pins load-issue order (R10 sink defense; R15
//    proved the idiom).
// Carried: plain stores (R8), natural VGPR (R7), margin-2 derived waits
// (R14 failure lesson), residuals from LDS tile (x read once).

constexpr int H     = 16;
constexpr int D     = 64;
constexpr int TPI   = 32;               // tokens per wave-iteration
constexpr int NIT   = 8;                // iterations per wave
constexpr int WAVES = 4;
constexpr int BT    = WAVES * TPI * NIT;   // 1024 tokens per block

typedef __attribute__((ext_vector_type(8))) short    short8;
typedef __attribute__((ext_vector_type(4))) float    floatx4;
typedef __attribute__((ext_vector_type(4))) unsigned uintx4;

__device__ inline unsigned pk2(float a, float b) { // low = a, high = b
    __hip_bfloat162 h = __float22bfloat162_rn(make_float2(a, b));
    unsigned u; __builtin_memcpy(&u, &h, 4); return u;
}
__device__ inline floatx4 relu4(floatx4 v) {
    v.x = fmaxf(v.x, 0.f); v.y = fmaxf(v.y, 0.f);
    v.z = fmaxf(v.z, 0.f); v.w = fmaxf(v.w, 0.f);
    return v;
}

// fc1 (4 m-tiles) -> relu -> register repack -> fc2 (2 k-tiles), C-in = b2.
__device__ inline floatx4 tile_ffn(const short8* a1, const short8* a2,
                                   floatx4 c2, short8 by) {
    const floatx4 z = {0.f, 0.f, 0.f, 0.f};
    floatx4 h0 = relu4(__builtin_amdgcn_mfma_f32_16x16x32_bf16(a1[0], by, z, 0, 0, 0));
    floatx4 h1 = relu4(__builtin_amdgcn_mfma_f32_16x16x32_bf16(a1[1], by, z, 0, 0, 0));
    floatx4 h2 = relu4(__builtin_amdgcn_mfma_f32_16x16x32_bf16(a1[2], by, z, 0, 0, 0));
    floatx4 h3 = relu4(__builtin_amdgcn_mfma_f32_16x16x32_bf16(a1[3], by, z, 0, 0, 0));
    uintx4 r0 = { pk2(h0.x, h0.y), pk2(h0.z, h0.w), pk2(h1.x, h1.y), pk2(h1.z, h1.w) };
    uintx4 r1 = { pk2(h2.x, h2.y), pk2(h2.z, h2.w), pk2(h3.x, h3.y), pk2(h3.z, h3.w) };
    short8 bh0, bh1;
    __builtin_memcpy(&bh0, &r0, 16);
    __builtin_memcpy(&bh1, &r1, 16);
    floatx4 o = __builtin_amdgcn_mfma_f32_16x16x32_bf16(a2[0], bh0, c2, 0, 0, 0);
    o = __builtin_amdgcn_mfma_f32_16x16x32_bf16(a2[1], bh1, o, 0, 0, 0);
    return o;
}

__global__ __launch_bounds__(256, 4) void ffn_kernel(
    const float* __restrict__ x,
    const float* __restrict__ ln_g,
    const float* __restrict__ ln_b,
    const float* __restrict__ w1,
    const float* __restrict__ b1,
    const float* __restrict__ w2,
    const float* __restrict__ b2,
    float* __restrict__ out,
    int ntok)
{
    __shared__ float sx[WAVES][TPI * H];   // 4 x 2KB = 8KB (single slot/wave)

    const int tid = threadIdx.x;
    const int w = tid >> 6, l = tid & 63;
    const int li = l & 15, q = l >> 4;
    const int hb = q >> 1;           // 0: this lane's LN covers tile-A, 1: tile-B
    const int k0 = (q & 1) * 8;      // feature base this lane covers

    const int tok0 = blockIdx.x * BT + w * (TPI * NIT);

    // reg-staging: lane l holds chunks l and 64+l (16B each) of the 2KB tile.
    // 4 slots x 8 VGPR; slot index (j&3) is compile-time in the unrolled loop.
    floatx4 sreg[4][2];
    #define LOADX(j_) do {                                                   \
        const float* g_ = x + (size_t)(tok0 + (j_) * TPI) * H + 4 * l;       \
        sreg[(j_) & 3][0] = *(const floatx4*)(g_);                           \
        sreg[(j_) & 3][1] = *(const floatx4*)(g_ + 256);                     \
    } while (0)

    // prime: tiles 0..2 issued, ORDER PINNED (vmcnt count basis guaranteed)
    LOADX(0);
    asm volatile("" ::: "memory");
    LOADX(1);
    asm volatile("" ::: "memory");
    LOADX(2);
    asm volatile("" ::: "memory");

    // ---- per-lane weight fragments, direct from global (cache-resident) ----
    short8 a1[4];
    #pragma unroll
    for (int mt = 0; mt < 4; mt++) {
        const int d = 16 * mt + li;
        uintx4 u = {0u, 0u, 0u, 0u};
        if (q < 2) {
            floatx4 wa = *(const floatx4*)(w1 + d * H + k0);
            floatx4 wb = *(const floatx4*)(w1 + d * H + k0 + 4);
            u.x = pk2(wa.x, wa.y); u.y = pk2(wa.z, wa.w);
            u.z = pk2(wb.x, wb.y); u.w = pk2(wb.z, wb.w);
        } else if (q == 2) {
            u.x = pk2(b1[d], 0.f);   // k=16 slot carries b1 (B-side supplies 1.0)
        }
        __builtin_memcpy(&a1[mt], &u, 16);
    }
    short8 a2[2];
    #pragma unroll
    for (int kt = 0; kt < 2; kt++) {
        floatx4 wa = *(const floatx4*)(w2 + li * D + kt * 32 + 4 * q);
        floatx4 wb = *(const floatx4*)(w2 + li * D + kt * 32 + 16 + 4 * q);
        uintx4 u = { pk2(wa.x, wa.y), pk2(wa.z, wa.w), pk2(wb.x, wb.y), pk2(wb.z, wb.w) };
        __builtin_memcpy(&a2[kt], &u, 16);
    }
    const floatx4 c2 = *(const floatx4*)(b2 + 4 * q);
    const floatx4 ga = *(const floatx4*)(ln_g + k0);
    const floatx4 gb = *(const floatx4*)(ln_g + k0 + 4);
    const floatx4 ea = *(const floatx4*)(ln_b + k0);
    const floatx4 eb = *(const floatx4*)(ln_b + k0 + 4);

    #pragma unroll
    for (int it = 0; it < NIT; ++it) {
        if (it + 3 < NIT) LOADX(it + 3);
        asm volatile("" ::: "memory");

        // R15-verbatim derived waits (LOADX = 2 VMEM ops, same as STAGE was;
        // guaranteed-after counts from asm-pinned order, margin 2):
        if (it == 0)            asm volatile("s_waitcnt vmcnt(4)"  ::: "memory");
        else if (it == 1)       asm volatile("s_waitcnt vmcnt(6)"  ::: "memory");
        else if (it == 2)       asm volatile("s_waitcnt vmcnt(8)"  ::: "memory");
        else if (it < NIT - 3)  asm volatile("s_waitcnt vmcnt(10)" ::: "memory");
        else if (it == NIT - 3) asm volatile("s_waitcnt vmcnt(8)"  ::: "memory");
        else if (it == NIT - 2) asm volatile("s_waitcnt vmcnt(6)"  ::: "memory");
        else                    asm volatile("s_waitcnt vmcnt(4)"  ::: "memory");

        // reg slot -> wave-private LDS slot (layout identical to R15's tile)
        float* slot = &sx[w][0];
        *(floatx4*)&slot[4 * l]       = sreg[it & 3][0];
        *(floatx4*)&slot[256 + 4 * l] = sreg[it & 3][1];

        const float* tile = slot;
        // fragment: token tt = hb*16+li, features k0..k0+7
        const floatx4 xa = *(const floatx4*)&tile[(hb * 16 + li) * H + k0];
        const floatx4 xb = *(const floatx4*)&tile[(hb * 16 + li) * H + k0 + 4];
        // residuals (tile A: token li; tile B: token 16+li), floats 4q..4q+3
        const floatx4 xrA = *(const floatx4*)&tile[li * H + 4 * q];
        const floatx4 xrB = *(const floatx4*)&tile[(16 + li) * H + 4 * q];

        const int rA = (tok0 + it * TPI + li) * H + 4 * q;  // ntok*H < 2^31

        // ---- LN over this lane's 8 features (partner = lane^16) ----
        float ps = (xa.x + xa.y) + (xa.z + xa.w) + (xb.x + xb.y) + (xb.z + xb.w);
        float pq = 0.f;
        pq = fmaf(xa.x, xa.x, pq); pq = fmaf(xa.y, xa.y, pq);
        pq = fmaf(xa.z, xa.z, pq); pq = fmaf(xa.w, xa.w, pq);
        pq = fmaf(xb.x, xb.x, pq); pq = fmaf(xb.y, xb.y, pq);
        pq = fmaf(xb.z, xb.z, pq); pq = fmaf(xb.w, xb.w, pq);
        ps += __shfl_xor(ps, 16);
        pq += __shfl_xor(pq, 16);
        const float mean = ps * (1.0f / H);
        const float var  = fmaf(-mean, mean, pq * (1.0f / H));
        const float inv  = rsqrtf(var + 1e-5f);
        const float sa = inv, sb = -mean * inv;

        const float y0 = fmaf(fmaf(xa.x, sa, sb), ga.x, ea.x);
        const float y1 = fmaf(fmaf(xa.y, sa, sb), ga.y, ea.y);
        const float y2 = fmaf(fmaf(xa.z, sa, sb), ga.z, ea.z);
        const float y3 = fmaf(fmaf(xa.w, sa, sb), ga.w, ea.w);
        const float y4 = fmaf(fmaf(xb.x, sa, sb), gb.x, eb.x);
        const float y5 = fmaf(fmaf(xb.y, sa, sb), gb.y, eb.y);
        const float y6 = fmaf(fmaf(xb.z, sa, sb), gb.z, eb.z);
        const float y7 = fmaf(fmaf(xb.w, sa, sb), gb.w, eb.w);

        const unsigned p0 = pk2(y0, y1), p1 = pk2(y2, y3),
                       p2 = pk2(y4, y5), p3 = pk2(y6, y7);
        // hand tile-B's y (held by q>=2 lanes) to q<2 lanes, and vice versa
        const unsigned s0 = __shfl_xor(p0, 32), s1 = __shfl_xor(p1, 32),
                       s2 = __shfl_xor(p2, 32), s3 = __shfl_xor(p3, 32);

        const bool lo = (q < 2);
        const unsigned cq2 = (q == 2) ? 0x3F80u : 0u;  // bf16 1.0 at k=16 (b1 fold)
        uintx4 uA = { lo ? p0 : cq2, lo ? p1 : 0u, lo ? p2 : 0u, lo ? p3 : 0u };
        uintx4 uB = { lo ? s0 : cq2, lo ? s1 : 0u, lo ? s2 : 0u, lo ? s3 : 0u };
        short8 byA, byB;
        __builtin_memcpy(&byA, &uA, 16);
        __builtin_memcpy(&byB, &uB, 16);

        // ---- tile A: 16 tokens, residual + coalesced store ----
        floatx4 oA = tile_ffn(a1, a2, c2, byA);
        oA += xrA;
        *(floatx4*)(out + rA) = oA;
        // ---- tile B ----
        floatx4 oB = tile_ffn(a1, a2, c2, byB);
        oB += xrB;
        *(floatx4*)(out + rA + 16 * H) = oB;
    }
    #undef LOADX
    (void)ntok;
}

extern "C" void kernel_launch(void* const* d_in, const int* in_sizes, int n_in,
                              void* d_out, int out_size, void* d_ws, size_t ws_size,
                              hipStream_t stream) {
    const float* x   = (const float*)d_in[0];
    const float* g   = (const float*)d_in[1];
    const float* be  = (const float*)d_in[2];
    const float* w1  = (const float*)d_in[3];
    const float* b1  = (const float*)d_in[4];
    const float* w2  = (const float*)d_in[5];
    const float* b2  = (const float*)d_in[6];
    float* out = (float*)d_out;
    const int ntok = in_sizes[0] / H;      // 1048576, divisible by BT=1024

    const int grid = ntok / BT;            // 1024 blocks of 256 threads
    ffn_kernel<<<grid, 256, 0, stream>>>(x, g, be, w1, b1, w2, b2, out, ntok);
}

// Round 15
// 126.179 us; speedup vs baseline: 1.0095x; 1.0095x over previous
//
#include <hip/hip_runtime.h>
#include <hip/hip_bf16.h>

// FFN: out = x + fc2(relu(fc1(LN(x)))), x:(ntok,16) fp32, ntok % 1024 == 0.
// R17: R15 (DMA depth-3, counted vmcnt — best at ~124.7 bench) + LDS
// XOR-swizzle. Diagnosis: token-major tile (64B row stride) makes every
// fragment/residual ds_read_b128 an 8-way bank conflict (lanes li=0..15
// start at byte li*64 -> 2 bank-groups); 4 conflicted reads x 16 waves x
// 8 iters ~ the entire 2x gap to the streaming floor. Fix (rule #21:
// both-sides-or-neither, m173 pattern — LDS dest stays linear):
//  - involution on 16B chunks: f(c) = c ^ ((c>>3)&3)
//  - STAGE global source chunk = l ^ ((l>>3)&3)  (second load: +64, formula
//    invariant since 64 ≡ 0 mod 4 in the XOR field)
//  - all reads XOR their chunk index with mswz = (li>>1)&3 (constant per
//    lane for fragment AND residual reads — derived, loop-invariant)
// Post-swizzle: fragment read = 64 distinct chunks (minimum-time),
// residuals likewise; 2-way residue is free (m136).
// Carried: R15 prologue pinning + margin-2 derived waits (R14 race lesson),
// plain stores (R8), natural VGPR (R7), x read exactly once.

constexpr int H     = 16;
constexpr int D     = 64;
constexpr int TPI   = 32;               // tokens per wave-iteration
constexpr int NIT   = 8;                // iterations per wave
constexpr int WAVES = 4;
constexpr int SLOTS = 4;                // LDS buffer slots (prefetch depth 3)
constexpr int BT    = WAVES * TPI * NIT;   // 1024 tokens per block

typedef __attribute__((ext_vector_type(8))) short    short8;
typedef __attribute__((ext_vector_type(4))) float    floatx4;
typedef __attribute__((ext_vector_type(4))) unsigned uintx4;

__device__ inline unsigned pk2(float a, float b) { // low = a, high = b
    __hip_bfloat162 h = __float22bfloat162_rn(make_float2(a, b));
    unsigned u; __builtin_memcpy(&u, &h, 4); return u;
}
__device__ inline floatx4 relu4(floatx4 v) {
    v.x = fmaxf(v.x, 0.f); v.y = fmaxf(v.y, 0.f);
    v.z = fmaxf(v.z, 0.f); v.w = fmaxf(v.w, 0.f);
    return v;
}

// fc1 (4 m-tiles) -> relu -> register repack -> fc2 (2 k-tiles), C-in = b2.
__device__ inline floatx4 tile_ffn(const short8* a1, const short8* a2,
                                   floatx4 c2, short8 by) {
    const floatx4 z = {0.f, 0.f, 0.f, 0.f};
    floatx4 h0 = relu4(__builtin_amdgcn_mfma_f32_16x16x32_bf16(a1[0], by, z, 0, 0, 0));
    floatx4 h1 = relu4(__builtin_amdgcn_mfma_f32_16x16x32_bf16(a1[1], by, z, 0, 0, 0));
    floatx4 h2 = relu4(__builtin_amdgcn_mfma_f32_16x16x32_bf16(a1[2], by, z, 0, 0, 0));
    floatx4 h3 = relu4(__builtin_amdgcn_mfma_f32_16x16x32_bf16(a1[3], by, z, 0, 0, 0));
    uintx4 r0 = { pk2(h0.x, h0.y), pk2(h0.z, h0.w), pk2(h1.x, h1.y), pk2(h1.z, h1.w) };
    uintx4 r1 = { pk2(h2.x, h2.y), pk2(h2.z, h2.w), pk2(h3.x, h3.y), pk2(h3.z, h3.w) };
    short8 bh0, bh1;
    __builtin_memcpy(&bh0, &r0, 16);
    __builtin_memcpy(&bh1, &r1, 16);
    floatx4 o = __builtin_amdgcn_mfma_f32_16x16x32_bf16(a2[0], bh0, c2, 0, 0, 0);
    o = __builtin_amdgcn_mfma_f32_16x16x32_bf16(a2[1], bh1, o, 0, 0, 0);
    return o;
}

__global__ __launch_bounds__(256, 4) void ffn_kernel(
    const float* __restrict__ x,
    const float* __restrict__ ln_g,
    const float* __restrict__ ln_b,
    const float* __restrict__ w1,
    const float* __restrict__ b1,
    const float* __restrict__ w2,
    const float* __restrict__ b2,
    float* __restrict__ out,
    int ntok)
{
    __shared__ float sx[WAVES][SLOTS][TPI * H];   // 4 x 4 x 2KB = 32KB

    const int tid = threadIdx.x;
    const int w = tid >> 6, l = tid & 63;
    const int li = l & 15, q = l >> 4;
    const int hb = q >> 1;           // 0: this lane's LN covers tile-A, 1: tile-B
    const int k0 = (q & 1) * 8;      // feature base this lane covers

    const int tok0 = blockIdx.x * BT + w * (TPI * NIT);

    // swizzled DMA source: LDS chunk l holds global chunk l^((l>>3)&3)
    const int gswz = (l ^ ((l >> 3) & 3)) * 4;   // float offset within tile

    #define STAGE(j_) do {                                                       \
        const int s_ = (j_) % SLOTS;                                             \
        const float* g_ = x + (size_t)(tok0 + (j_) * TPI) * H + gswz;            \
        __builtin_amdgcn_global_load_lds(                                        \
            (const __attribute__((address_space(1))) void*)(g_),                 \
            (__attribute__((address_space(3))) void*)&sx[w][s_][0], 16, 0, 0);   \
        __builtin_amdgcn_global_load_lds(                                        \
            (const __attribute__((address_space(1))) void*)(g_ + 256),           \
            (__attribute__((address_space(3))) void*)&sx[w][s_][256], 16, 0, 0); \
    } while (0)

    // prime: tiles 0..2 in flight, ORDER PINNED (vmcnt count basis guaranteed)
    STAGE(0);
    asm volatile("" ::: "memory");
    STAGE(1);
    asm volatile("" ::: "memory");
    STAGE(2);
    asm volatile("" ::: "memory");

    // swizzled read offsets (loop-invariant; mask = (li>>1)&3 for ALL reads)
    const int mswz = (li >> 1) & 3;
    const int cA   = (hb * 16 + li) * 4 + 2 * (q & 1);       // fragment chunk
    const int offA  = (cA ^ mswz) * 4;                       // xa (16B)
    const int offB  = ((cA + 1) ^ mswz) * 4;                 // xb (16B)
    const int offRA = (((4 * li + q) ^ mswz)) * 4;           // residual tile A
    const int offRB = offRA + 256;                           // residual tile B

    // ---- per-lane weight fragments, direct from global (cache-resident) ----
    short8 a1[4];
    #pragma unroll
    for (int mt = 0; mt < 4; mt++) {
        const int d = 16 * mt + li;
        uintx4 u = {0u, 0u, 0u, 0u};
        if (q < 2) {
            floatx4 wa = *(const floatx4*)(w1 + d * H + k0);
            floatx4 wb = *(const floatx4*)(w1 + d * H + k0 + 4);
            u.x = pk2(wa.x, wa.y); u.y = pk2(wa.z, wa.w);
            u.z = pk2(wb.x, wb.y); u.w = pk2(wb.z, wb.w);
        } else if (q == 2) {
            u.x = pk2(b1[d], 0.f);   // k=16 slot carries b1 (B-side supplies 1.0)
        }
        __builtin_memcpy(&a1[mt], &u, 16);
    }
    short8 a2[2];
    #pragma unroll
    for (int kt = 0; kt < 2; kt++) {
        floatx4 wa = *(const floatx4*)(w2 + li * D + kt * 32 + 4 * q);
        floatx4 wb = *(const floatx4*)(w2 + li * D + kt * 32 + 16 + 4 * q);
        uintx4 u = { pk2(wa.x, wa.y), pk2(wa.z, wa.w), pk2(wb.x, wb.y), pk2(wb.z, wb.w) };
        __builtin_memcpy(&a2[kt], &u, 16);
    }
    const floatx4 c2 = *(const floatx4*)(b2 + 4 * q);
    const floatx4 ga = *(const floatx4*)(ln_g + k0);
    const floatx4 gb = *(const floatx4*)(ln_g + k0 + 4);
    const floatx4 ea = *(const floatx4*)(ln_b + k0);
    const floatx4 eb = *(const floatx4*)(ln_b + k0 + 4);

    #pragma unroll
    for (int it = 0; it < NIT; ++it) {
        if (it + 3 < NIT) STAGE(it + 3);

        // R15-verbatim derived waits (guaranteed-after counts, margin 2)
        if (it == 0)            asm volatile("s_waitcnt vmcnt(4)"  ::: "memory");
        else if (it == 1)       asm volatile("s_waitcnt vmcnt(6)"  ::: "memory");
        else if (it == 2)       asm volatile("s_waitcnt vmcnt(8)"  ::: "memory");
        else if (it < NIT - 3)  asm volatile("s_waitcnt vmcnt(10)" ::: "memory");
        else if (it == NIT - 3) asm volatile("s_waitcnt vmcnt(8)"  ::: "memory");
        else if (it == NIT - 2) asm volatile("s_waitcnt vmcnt(6)"  ::: "memory");
        else                    asm volatile("s_waitcnt vmcnt(4)"  ::: "memory");

        const float* tile = sx[w][it % SLOTS];
        // swizzled reads (conflict-free: 64 distinct chunks per access)
        const floatx4 xa  = *(const floatx4*)&tile[offA];
        const floatx4 xb  = *(const floatx4*)&tile[offB];
        const floatx4 xrA = *(const floatx4*)&tile[offRA];
        const floatx4 xrB = *(const floatx4*)&tile[offRB];

        const int rA = (tok0 + it * TPI + li) * H + 4 * q;  // ntok*H < 2^31

        // ---- LN over this lane's 8 features (partner = lane^16) ----
        float ps = (xa.x + xa.y) + (xa.z + xa.w) + (xb.x + xb.y) + (xb.z + xb.w);
        float pq = 0.f;
        pq = fmaf(xa.x, xa.x, pq); pq = fmaf(xa.y, xa.y, pq);
        pq = fmaf(xa.z, xa.z, pq); pq = fmaf(xa.w, xa.w, pq);
        pq = fmaf(xb.x, xb.x, pq); pq = fmaf(xb.y, xb.y, pq);
        pq = fmaf(xb.z, xb.z, pq); pq = fmaf(xb.w, xb.w, pq);
        ps += __shfl_xor(ps, 16);
        pq += __shfl_xor(pq, 16);
        const float mean = ps * (1.0f / H);
        const float var  = fmaf(-mean, mean, pq * (1.0f / H));
        const float inv  = rsqrtf(var + 1e-5f);
        const float sa = inv, sb = -mean * inv;

        const float y0 = fmaf(fmaf(xa.x, sa, sb), ga.x, ea.x);
        const float y1 = fmaf(fmaf(xa.y, sa, sb), ga.y, ea.y);
        const float y2 = fmaf(fmaf(xa.z, sa, sb), ga.z, ea.z);
        const float y3 = fmaf(fmaf(xa.w, sa, sb), ga.w, ea.w);
        const float y4 = fmaf(fmaf(xb.x, sa, sb), gb.x, eb.x);
        const float y5 = fmaf(fmaf(xb.y, sa, sb), gb.y, eb.y);
        const float y6 = fmaf(fmaf(xb.z, sa, sb), gb.z, eb.z);
        const float y7 = fmaf(fmaf(xb.w, sa, sb), gb.w, eb.w);

        const unsigned p0 = pk2(y0, y1), p1 = pk2(y2, y3),
                       p2 = pk2(y4, y5), p3 = pk2(y6, y7);
        // hand tile-B's y (held by q>=2 lanes) to q<2 lanes, and vice versa
        const unsigned s0 = __shfl_xor(p0, 32), s1 = __shfl_xor(p1, 32),
                       s2 = __shfl_xor(p2, 32), s3 = __shfl_xor(p3, 32);

        const bool lo = (q < 2);
        const unsigned cq2 = (q == 2) ? 0x3F80u : 0u;  // bf16 1.0 at k=16 (b1 fold)
        uintx4 uA = { lo ? p0 : cq2, lo ? p1 : 0u, lo ? p2 : 0u, lo ? p3 : 0u };
        uintx4 uB = { lo ? s0 : cq2, lo ? s1 : 0u, lo ? s2 : 0u, lo ? s3 : 0u };
        short8 byA, byB;
        __builtin_memcpy(&byA, &uA, 16);
        __builtin_memcpy(&byB, &uB, 16);

        // ---- tile A: 16 tokens, residual + coalesced store ----
        floatx4 oA = tile_ffn(a1, a2, c2, byA);
        oA += xrA;
        *(floatx4*)(out + rA) = oA;
        // ---- tile B ----
        floatx4 oB = tile_ffn(a1, a2, c2, byB);
        oB += xrB;
        *(floatx4*)(out + rA + 16 * H) = oB;
    }
    #undef STAGE
    (void)ntok;
}

extern "C" void kernel_launch(void* const* d_in, const int* in_sizes, int n_in,
                              void* d_out, int out_size, void* d_ws, size_t ws_size,
                              hipStream_t stream) {
    const float* x   = (const float*)d_in[0];
    const float* g   = (const float*)d_in[1];
    const float* be  = (const float*)d_in[2];
    const float* w1  = (const float*)d_in[3];
    const float* b1  = (const float*)d_in[4];
    const float* w2  = (const float*)d_in[5];
    const float* b2  = (const float*)d_in[6];
    float* out = (float*)d_out;
    const int ntok = in_sizes[0] / H;      // 1048576, divisible by BT=1024

    const int grid = ntok / BT;            // 1024 blocks of 256 threads
    ffn_kernel<<<grid, 256, 0, stream>>>(x, g, be, w1, b1, w2, b2, out, ntok);
}